// Round 1
// baseline (105.512 us; speedup 1.0000x reference)
//
#include <hip/hip_runtime.h>
#include <cstddef>

// ExpFilter: out[t] = y[t] + d*out[t-1],  y = X @ W^T + b
// T=2048 B=32 I=256 O=256, d = exp(-1).
// K0: split W -> bf16 hi/lo (ws). K1: split-bf16 MFMA GEMM -> y (ws, fp32).
// K2: chunked scan (64-step chunks, 24-step warmup; d^25 ~ 1.4e-11 => carry negligible).

#define DECAY 0.36787944117144233f

typedef __attribute__((ext_vector_type(8))) short short8;
typedef __attribute__((ext_vector_type(4))) float f32x4;

static constexpr int T_DIM = 2048, B_DIM = 32;
static constexpr int M_DIM = T_DIM * B_DIM;   // 65536
static constexpr int K_DIM = 256, N_DIM = 256;

__device__ __forceinline__ float bfbits2f(unsigned short u) {
  unsigned int x = ((unsigned int)u) << 16;
  return __builtin_bit_cast(float, x);
}
__device__ __forceinline__ short f2bf_s(float f) {
  __bf16 h = (__bf16)f;                 // RTNE (split is self-correcting anyway)
  return __builtin_bit_cast(short, h);
}

// ---------------- K0: W (fp32 [O][I]) -> W_hi, W_lo bf16 same layout ----------------
__global__ void k_split_w(const float* __restrict__ W, short* __restrict__ Wh,
                          short* __restrict__ Wl) {
  int i = blockIdx.x * 256 + threadIdx.x;
  float w = W[i];
  short h = f2bf_s(w);
  float r = w - bfbits2f((unsigned short)h);
  Wh[i] = h;
  Wl[i] = f2bf_s(r);
}

// ---------------- K1: y = X @ W^T + b via 3-MFMA split-bf16 ----------------
// block: 512 thr = 8 waves = 2 rowgroups(64) x 4 colgroups(64); block tile 128 x 256.
// W_hi full [256][256] bf16 in LDS (128 KiB), XOR-swizzled: byte ^= (o&7)<<4.
// W_lo B-frags read from global (L2-resident, 128 KiB).
__global__ __launch_bounds__(512, 2)
void k_gemm(const float* __restrict__ X, const short* __restrict__ Wh,
            const short* __restrict__ Wl, const float* __restrict__ bias,
            float* __restrict__ Y) {
  __shared__ short lds_wh[N_DIM * K_DIM];   // 128 KiB

  const int tid = threadIdx.x;

  // stage W_hi -> LDS (16B chunks), swizzled
  #pragma unroll
  for (int i = 0; i < 16; ++i) {
    int ch = tid + i * 512;            // 8192 chunks of 8 bf16
    int o  = ch >> 5;                  // 32 chunks per 256-elem row
    int kc = ch & 31;
    short8 v = *reinterpret_cast<const short8*>(Wh + o * 256 + kc * 8);
    int byte = (o << 9) + (kc << 4);
    byte ^= (o & 7) << 4;
    *reinterpret_cast<short8*>(reinterpret_cast<char*>(lds_wh) + byte) = v;
  }
  __syncthreads();

  const int lane  = tid & 63;
  const int wave  = tid >> 6;
  const int cg    = wave & 3;          // col group (x64)
  const int rg    = wave >> 2;         // row group (x64)
  const int row16 = lane & 15;
  const int kq    = lane >> 4;         // 0..3
  const int mbase = blockIdx.x * 128 + rg * 64;

  f32x4 acc[4][4] = {};

  #pragma unroll 2
  for (int kt = 0; kt < 8; ++kt) {
    const int k0 = kt * 32 + kq * 8;

    // A fragments: rows mbase + rt*16 + row16, k = k0..k0+7 (fp32 -> split bf16)
    short8 ahi[4], alo[4];
    #pragma unroll
    for (int rt = 0; rt < 4; ++rt) {
      const float* ap = X + (size_t)(mbase + rt * 16 + row16) * 256 + k0;
      f32x4 a0 = *reinterpret_cast<const f32x4*>(ap);
      f32x4 a1 = *reinterpret_cast<const f32x4*>(ap + 4);
      #pragma unroll
      for (int j = 0; j < 4; ++j) {
        float f0 = a0[j], f1 = a1[j];
        short h0 = f2bf_s(f0), h1 = f2bf_s(f1);
        ahi[rt][j]     = h0;
        ahi[rt][j + 4] = h1;
        alo[rt][j]     = f2bf_s(f0 - bfbits2f((unsigned short)h0));
        alo[rt][j + 4] = f2bf_s(f1 - bfbits2f((unsigned short)h1));
      }
    }

    // B fragments: col o = cg*64 + ct*16 + row16, same k range
    short8 bhi[4], blo[4];
    #pragma unroll
    for (int ct = 0; ct < 4; ++ct) {
      int o = cg * 64 + ct * 16 + row16;
      int byte = (o << 9) + (kt << 6) + (kq << 4);
      byte ^= (o & 7) << 4;
      bhi[ct] = *reinterpret_cast<const short8*>(
          reinterpret_cast<const char*>(lds_wh) + byte);
      blo[ct] = *reinterpret_cast<const short8*>(Wl + (size_t)o * 256 + k0);
    }

    #pragma unroll
    for (int rt = 0; rt < 4; ++rt)
      #pragma unroll
      for (int ct = 0; ct < 4; ++ct) {
        acc[rt][ct] = __builtin_amdgcn_mfma_f32_16x16x32_bf16(ahi[rt], bhi[ct], acc[rt][ct], 0, 0, 0);
        acc[rt][ct] = __builtin_amdgcn_mfma_f32_16x16x32_bf16(alo[rt], bhi[ct], acc[rt][ct], 0, 0, 0);
        acc[rt][ct] = __builtin_amdgcn_mfma_f32_16x16x32_bf16(ahi[rt], blo[ct], acc[rt][ct], 0, 0, 0);
      }
  }

  // epilogue: C/D layout col = lane&15, row = (lane>>4)*4 + j  [m89-verified]
  #pragma unroll
  for (int ct = 0; ct < 4; ++ct) {
    int col = cg * 64 + ct * 16 + row16;
    float bv = bias[col];
    #pragma unroll
    for (int rt = 0; rt < 4; ++rt) {
      int m0 = mbase + rt * 16 + kq * 4;
      #pragma unroll
      for (int j = 0; j < 4; ++j)
        Y[(size_t)(m0 + j) * 256 + col] = acc[rt][ct][j] + bv;
    }
  }
}

// ---------------- K2: chunked scan with warmup ----------------
// chunk = 64 timesteps, warmup = 24 (d^25 * |s| < 1e-10, below fp32 noise)
__global__ __launch_bounds__(256)
void k_scan(const float* __restrict__ Y, float* __restrict__ Out) {
  const int ch = blockIdx.x * 256 + threadIdx.x;   // 0..8191  (b*256+o)
  const int t0 = blockIdx.y * 64;
  const int ts = (t0 >= 24) ? (t0 - 24) : 0;
  const float d = DECAY;
  float s = 0.f;
  const float* p = Y + (size_t)ts * 8192 + ch;
  for (int t = ts; t < t0; ++t) { s = fmaf(d, s, *p); p += 8192; }
  float* q = Out + (size_t)t0 * 8192 + ch;
  #pragma unroll 4
  for (int i = 0; i < 64; ++i) {
    s = fmaf(d, s, *p); p += 8192;
    *q = s; q += 8192;
  }
}

// ---------------- fallback (ws too small): naive fp32, serial in-place scan ----------------
__global__ void k_fb_gemm(const float* __restrict__ X, const float* __restrict__ W,
                          const float* __restrict__ bias, float* __restrict__ Y) {
  size_t idx = (size_t)blockIdx.x * 256 + threadIdx.x;
  int o = (int)(idx & 255);
  size_t m = idx >> 8;
  const float* x = X + m * 256;
  const float* w = W + (size_t)o * 256;
  float s = bias[o];
  for (int k = 0; k < 256; ++k) s = fmaf(x[k], w[k], s);
  Y[idx] = s;
}
__global__ void k_fb_scan(float* __restrict__ Y) {
  int ch = blockIdx.x * 256 + threadIdx.x;
  float s = 0.f;
  float* p = Y + ch;
  for (int t = 0; t < 2048; ++t) { s = fmaf(DECAY, s, *p); *p = s; p += 8192; }
}

extern "C" void kernel_launch(void* const* d_in, const int* in_sizes, int n_in,
                              void* d_out, int out_size, void* d_ws, size_t ws_size,
                              hipStream_t stream) {
  const float* X    = (const float*)d_in[0];
  const float* W    = (const float*)d_in[1];
  const float* bias = (const float*)d_in[2];
  float* out = (float*)d_out;

  const size_t w_bytes = (size_t)N_DIM * K_DIM * 2 * sizeof(short);          // Wh+Wl = 256 KiB
  const size_t need    = w_bytes + (size_t)M_DIM * N_DIM * sizeof(float);    // + y = 64 MiB

  if (ws_size >= need) {
    short* Wh = (short*)d_ws;
    short* Wl = Wh + N_DIM * K_DIM;
    float* Y  = (float*)((char*)d_ws + w_bytes);
    k_split_w<<<N_DIM * K_DIM / 256, 256, 0, stream>>>(W, Wh, Wl);
    k_gemm<<<M_DIM / 128, 512, 0, stream>>>(X, Wh, Wl, bias, Y);
    k_scan<<<dim3(32, 32), 256, 0, stream>>>(Y, out);
  } else {
    k_fb_gemm<<<M_DIM, 256, 0, stream>>>(X, W, bias, out);
    k_fb_scan<<<32, 256, 0, stream>>>(out);
  }
}

// Round 2
// 104.128 us; speedup vs baseline: 1.0133x; 1.0133x over previous
//
#include <hip/hip_runtime.h>
#include <cstddef>

// ExpFilter fused: out[t] = y[t] + d*out[t-1],  y = X @ W^T + b,  d = exp(-1)
// T=2048 B=32 I=256 O=256.
// K0: split W -> bf16 hi/lo.
// K1: fused GEMM+scan. Block = (b, 128-t chunk + 32 warmup), all 256 o.
//     Per 32-t tile: X->regs->split bf16->swizzled LDS; MFMA (3-term split,
//     W_hi in regs, W_lo streamed from L2); y tile -> LDS; per-channel serial
//     scan (carry in reg across tiles); coalesced store. Y never hits HBM.

#define DECAY 0.36787944117144233f

typedef __attribute__((ext_vector_type(8))) short short8;
typedef __attribute__((ext_vector_type(4))) float f32x4;

static constexpr int T_DIM = 2048, B_DIM = 32, K_DIM = 256, N_DIM = 256;
static constexpr int M_DIM = T_DIM * B_DIM;
static constexpr int CHUNK = 128;   // output timesteps per block
static constexpr int WARM  = 32;    // warmup steps; d^33 ~ 5e-15 => carry negligible
static constexpr int TT    = 32;    // timesteps per tile

__device__ __forceinline__ float bfbits2f(unsigned short u) {
  unsigned int x = ((unsigned int)u) << 16;
  return __builtin_bit_cast(float, x);
}
__device__ __forceinline__ short f2bf_s(float f) {
  __bf16 h = (__bf16)f;
  return __builtin_bit_cast(short, h);
}

// ---------------- K0: W (fp32 [O][I]) -> W_hi, W_lo bf16 ----------------
__global__ void k_split_w(const float* __restrict__ W, short* __restrict__ Wh,
                          short* __restrict__ Wl) {
  int i = blockIdx.x * 256 + threadIdx.x;
  float w = W[i];
  short h = f2bf_s(w);
  Wh[i] = h;
  Wl[i] = f2bf_s(w - bfbits2f((unsigned short)h));
}

// ---------------- K1: fused GEMM + scan ----------------
__global__ __launch_bounds__(256, 2)
void k_fused(const float* __restrict__ X, const short* __restrict__ Wh,
             const short* __restrict__ Wl, const float* __restrict__ bias,
             float* __restrict__ out) {
  // Ah [32][256] bf16 @0, Al @16384; byte ^= (row&7)<<4 swizzle
  __shared__ __align__(16) char lds_a[32768];
  __shared__ float lds_y[TT][260];   // +4 pad: epilogue/scan <=2-way banks

  const int b      = blockIdx.x;     // 0..31
  const int c      = blockIdx.y;     // 0..15
  const int t0     = c * CHUNK;
  const int tstart = (c == 0) ? 0 : t0 - WARM;
  const int ntile  = (c == 0) ? (CHUNK / TT) : ((CHUNK + WARM) / TT);

  const int tid   = threadIdx.x;
  const int lane  = tid & 63;
  const int wv    = tid >> 6;        // 0..3, owns o-cols wv*64..+64
  const int row16 = lane & 15;
  const int kq    = lane >> 4;       // 0..3

  // ---- W_hi fragments resident in registers: bh[cf][kt] (128 VGPR) ----
  short8 bh[4][8];
  #pragma unroll
  for (int cf = 0; cf < 4; ++cf) {
    const int col = wv * 64 + cf * 16 + row16;
    #pragma unroll
    for (int kt = 0; kt < 8; ++kt)
      bh[cf][kt] = *reinterpret_cast<const short8*>(
          Wh + (size_t)col * 256 + kt * 32 + kq * 8);
  }

  // staging map: thread -> (row srow of tile, 32 consecutive k at scol)
  const int srow = tid >> 3;         // 0..31
  const int scol = (tid & 7) * 32;   // 0..224

  // prefetch tile 0 into registers (128 B contiguous per thread)
  f32x4 xr[8];
  {
    const float* p = X + ((size_t)(tstart + srow) * 32 + b) * 256 + scol;
    #pragma unroll
    for (int j = 0; j < 8; ++j) xr[j] = *reinterpret_cast<const f32x4*>(p + 4 * j);
  }

  float s = 0.f;                     // scan carry; thread owns channel o = tid
  const float bv = bias[tid];
  const float d  = DECAY;

  for (int it = 0; it < ntile; ++it) {
    // ---- convert prefetched X regs -> bf16 hi/lo -> swizzled LDS ----
    #pragma unroll
    for (int q = 0; q < 4; ++q) {
      short8 hi, lo;
      #pragma unroll
      for (int h = 0; h < 2; ++h)
        #pragma unroll
        for (int j = 0; j < 4; ++j) {
          float f = xr[2 * q + h][j];
          short hs = f2bf_s(f);
          hi[h * 4 + j] = hs;
          lo[h * 4 + j] = f2bf_s(f - bfbits2f((unsigned short)hs));
        }
      int byte = srow * 512 + (scol + 8 * q) * 2;
      byte ^= (srow & 7) << 4;
      *reinterpret_cast<short8*>(lds_a + byte)         = hi;
      *reinterpret_cast<short8*>(lds_a + 16384 + byte) = lo;
    }
    __syncthreads();   // B1: lds_a ready; all prior scan reads of lds_y done

    // ---- T14: issue next tile's global loads before compute ----
    if (it + 1 < ntile) {
      const float* p =
          X + ((size_t)(tstart + (it + 1) * TT + srow) * 32 + b) * 256 + scol;
      #pragma unroll
      for (int j = 0; j < 8; ++j) xr[j] = *reinterpret_cast<const f32x4*>(p + 4 * j);
    }

    // ---- GEMM: wave computes 32t x 64o, K=256, 3-MFMA split ----
    f32x4 acc[2][4] = {};
    #pragma unroll
    for (int kt = 0; kt < 8; ++kt) {
      short8 ah[2], al[2];
      #pragma unroll
      for (int mf = 0; mf < 2; ++mf) {
        int r = mf * 16 + row16;
        int byte = r * 512 + (kt * 32 + kq * 8) * 2;
        byte ^= (r & 7) << 4;
        ah[mf] = *reinterpret_cast<const short8*>(lds_a + byte);
        al[mf] = *reinterpret_cast<const short8*>(lds_a + 16384 + byte);
      }
      #pragma unroll
      for (int cf = 0; cf < 4; ++cf) {
        const int col = wv * 64 + cf * 16 + row16;
        short8 bl = *reinterpret_cast<const short8*>(
            Wl + (size_t)col * 256 + kt * 32 + kq * 8);
        #pragma unroll
        for (int mf = 0; mf < 2; ++mf) {
          acc[mf][cf] = __builtin_amdgcn_mfma_f32_16x16x32_bf16(ah[mf], bh[cf][kt], acc[mf][cf], 0, 0, 0);
          acc[mf][cf] = __builtin_amdgcn_mfma_f32_16x16x32_bf16(al[mf], bh[cf][kt], acc[mf][cf], 0, 0, 0);
          acc[mf][cf] = __builtin_amdgcn_mfma_f32_16x16x32_bf16(ah[mf], bl,         acc[mf][cf], 0, 0, 0);
        }
      }
    }

    // ---- epilogue: acc -> lds_y (C/D: col=lane&15, row=kq*4+j) ----
    #pragma unroll
    for (int mf = 0; mf < 2; ++mf)
      #pragma unroll
      for (int cf = 0; cf < 4; ++cf) {
        const int o = wv * 64 + cf * 16 + row16;
        #pragma unroll
        for (int j = 0; j < 4; ++j)
          lds_y[mf * 16 + kq * 4 + j][o] = acc[mf][cf][j];
      }
    __syncthreads();   // B2: lds_y ready

    // ---- scan: thread owns channel o = tid; 32 serial steps ----
    const bool do_store = (c == 0) || (it >= 1);
    const int tglob = tstart + it * TT;
    float* op = out + (size_t)tglob * 8192 + b * 256 + tid;
    #pragma unroll
    for (int tb = 0; tb < 4; ++tb) {
      float v[8];
      #pragma unroll
      for (int j = 0; j < 8; ++j) v[j] = lds_y[tb * 8 + j][tid];
      #pragma unroll
      for (int j = 0; j < 8; ++j) {
        s = fmaf(d, s, v[j] + bv);
        if (do_store) op[(size_t)(tb * 8 + j) * 8192] = s;
      }
    }
    // no barrier needed: next convert writes lds_a (disjoint from lds_y);
    // next epilogue write of lds_y is separated from these reads by B1.
  }
}

// ---------------- fallback (ws too small): naive fp32 ----------------
__global__ void k_fb_gemm(const float* __restrict__ X, const float* __restrict__ W,
                          const float* __restrict__ bias, float* __restrict__ Y) {
  size_t idx = (size_t)blockIdx.x * 256 + threadIdx.x;
  int o = (int)(idx & 255);
  size_t m = idx >> 8;
  const float* x = X + m * 256;
  const float* w = W + (size_t)o * 256;
  float s = bias[o];
  for (int k = 0; k < 256; ++k) s = fmaf(x[k], w[k], s);
  Y[idx] = s;
}
__global__ void k_fb_scan(float* __restrict__ Y) {
  int ch = blockIdx.x * 256 + threadIdx.x;
  float s = 0.f;
  float* p = Y + ch;
  for (int t = 0; t < 2048; ++t) { s = fmaf(DECAY, s, *p); *p = s; p += 8192; }
}

extern "C" void kernel_launch(void* const* d_in, const int* in_sizes, int n_in,
                              void* d_out, int out_size, void* d_ws, size_t ws_size,
                              hipStream_t stream) {
  const float* X    = (const float*)d_in[0];
  const float* W    = (const float*)d_in[1];
  const float* bias = (const float*)d_in[2];
  float* out = (float*)d_out;

  const size_t w_bytes = (size_t)N_DIM * K_DIM * 2 * sizeof(short);  // 256 KiB

  if (ws_size >= w_bytes) {
    short* Wh = (short*)d_ws;
    short* Wl = Wh + N_DIM * K_DIM;
    k_split_w<<<N_DIM * K_DIM / 256, 256, 0, stream>>>(W, Wh, Wl);
    k_fused<<<dim3(B_DIM, T_DIM / CHUNK), 256, 0, stream>>>(X, Wh, Wl, bias, out);
  } else {
    k_fb_gemm<<<M_DIM, 256, 0, stream>>>(X, W, bias, out);
    k_fb_scan<<<32, 256, 0, stream>>>(out);
  }
}